// Round 18
// baseline (1210.861 us; speedup 1.0000x reference)
//
#include <hip/hip_runtime.h>
#include <math.h>

#define T_STEPS 512
#define BATCH   16
#define DIM     1024
#define M_TOTAL (T_STEPS*BATCH)              // 8192
#define OUT_SEC ((size_t)M_TOTAL*DIM)        // 8388608 floats (output section)
#define BD      (BATCH*DIM)

// ws: tagged ping-pong exchange, 2 slots x 16 batches x 1024 packets (8B)
#define TAG_BYTES ((size_t)2*BD*8)           // 256 KB

// prep grid: 512 GEMM blocks (128x128 tile) + 2048 gate blocks
#define NB_GEMM 512
#define NB_GATE 2048

// ---------------------------------------------------------------------------
__device__ __forceinline__ float wred64(float v){
  #pragma unroll
  for (int off = 32; off >= 1; off >>= 1) v += __shfl_xor(v, off, 64);
  return v;
}

// ---------------------------------------------------------------------------
// Prep (verified r17, ~205 us): blocks [0,512) = pre GEMM 128x128 tile with
// double-buffered staging; blocks [512,2560) = entmax-1.5 gate.
__global__ __launch_bounds__(256) void prep_kernel(const float* __restrict__ X,
                                                   const float* __restrict__ Wx,
                                                   const float* __restrict__ bias,
                                                   float* __restrict__ out_h,
                                                   const float* __restrict__ z,
                                                   float* __restrict__ gate_out){
  __shared__ float As[8][128];   // k-major A tile (4 KB)
  __shared__ float Bs[8][128];   // k-major B tile (4 KB)
  const int tid = threadIdx.x;

  if (blockIdx.x < NB_GEMM){
    const int bm = blockIdx.x >> 3;
    const int bn = blockIdx.x & 7;
    const int m0 = bm*128, n0 = bn*128;
    const int tx = tid & 15, ty = tid >> 4;
    const int sm = tid >> 1;
    const int sk = (tid & 1) * 4;

    float acc[8][8] = {};

    const float* Xp = X  + (size_t)(m0+sm)*DIM + sk;
    const float* Wp = Wx + (size_t)(n0+sm)*DIM + sk;

    float4 av = *reinterpret_cast<const float4*>(Xp);
    float4 wv = *reinterpret_cast<const float4*>(Wp);

    for (int k0 = 0; k0 < DIM; k0 += 8){
      __syncthreads();                  // previous compute done reading LDS
      As[sk+0][sm]=av.x; As[sk+1][sm]=av.y; As[sk+2][sm]=av.z; As[sk+3][sm]=av.w;
      Bs[sk+0][sm]=wv.x; Bs[sk+1][sm]=wv.y; Bs[sk+2][sm]=wv.z; Bs[sk+3][sm]=wv.w;
      const int kn = (k0 + 8 < DIM) ? (k0 + 8) : 0;
      const float4 av2 = *reinterpret_cast<const float4*>(Xp + kn);
      const float4 wv2 = *reinterpret_cast<const float4*>(Wp + kn);
      __syncthreads();
      #pragma unroll
      for (int k = 0; k < 8; ++k){
        float af[8], bf[8];
        #pragma unroll
        for (int i = 0; i < 8; ++i) af[i] = As[k][ty + 16*i];
        #pragma unroll
        for (int j = 0; j < 8; ++j) bf[j] = Bs[k][tx + 16*j];
        #pragma unroll
        for (int i = 0; i < 8; ++i)
          #pragma unroll
          for (int j = 0; j < 8; ++j) acc[i][j] = fmaf(af[i], bf[j], acc[i][j]);
      }
      av = av2; wv = wv2;
    }

    float bv[8];
    #pragma unroll
    for (int j = 0; j < 8; ++j) bv[j] = bias[n0 + tx + 16*j];
    #pragma unroll
    for (int i = 0; i < 8; ++i){
      float* dst = out_h + (size_t)(m0 + ty + 16*i + BATCH)*DIM + n0 + tx;
      #pragma unroll
      for (int j = 0; j < 8; ++j) dst[16*j] = acc[i][j] + bv[j];
    }
  } else {
    const int gb   = blockIdx.x - NB_GEMM;
    const int row  = gb * 4 + (tid >> 6);
    const int lane = tid & 63;
    const float* zr = z + (size_t)row * DIM;

    float x[16];
    #pragma unroll
    for (int e = 0; e < 4; ++e){
      float4 v = *reinterpret_cast<const float4*>(zr + e*256 + lane*4);
      x[e*4+0]=v.x; x[e*4+1]=v.y; x[e*4+2]=v.z; x[e*4+3]=v.w;
    }

    float m = x[0];
    #pragma unroll
    for (int i = 1; i < 16; ++i) m = fmaxf(m, x[i]);
    #pragma unroll
    for (int off = 32; off >= 1; off >>= 1) m = fmaxf(m, __shfl_xor(m, off, 64));

    float lo = m - 1.0f, hi = m;
    for (int it = 0; it < 30; ++it){
      float mid = 0.5f*(lo + hi);
      float f = 0.f;
      #pragma unroll
      for (int i = 0; i < 16; ++i) f += fmaxf(x[i] - mid, 0.f);
      f = wred64(f);
      if (f >= 1.0f) lo = mid; else hi = mid;
    }
    float s = 0.f, kc = 0.f;
    #pragma unroll
    for (int i = 0; i < 16; ++i){ if (x[i] > lo){ s += x[i]; kc += 1.f; } }
    s = wred64(s); kc = wred64(kc);
    const float tau = (s - 1.0f) / kc;

    float p[16]; float ps = 0.f;
    #pragma unroll
    for (int i = 0; i < 16; ++i){ p[i] = sqrtf(fmaxf(x[i] - tau, 0.f)); ps += p[i]; }
    ps = wred64(ps);
    const float inv = 1.0f / (ps + 1e-10f);

    float* go = gate_out + (size_t)row * DIM;
    #pragma unroll
    for (int e = 0; e < 4; ++e){
      float4 v; v.x=p[e*4]*inv; v.y=p[e*4+1]*inv; v.z=p[e*4+2]*inv; v.w=p[e*4+3]*inv;
      *reinterpret_cast<float4*>(go + e*256 + lane*4) = v;
    }
  }
}

// ---------------------------------------------------------------------------
// AGPR stash primitives (gfx950 unified VGPR/AGPR file). Weights are written
// to AGPRs ONCE before the t-loop and read back per use — synchronous VALU
// ops, no waitcnt, no in-flight-register phis (r16's hazard class absent).
#define AW(dst, src) asm volatile("v_accvgpr_write_b32 %0, %1" : "=a"(dst) : "v"(src))
#define AR(dst, src) asm volatile("v_accvgpr_read_b32 %0, %1"  : "=v"(dst) : "a"(src))

// Kernel C: r17 protocol (self-flagging packets, distributed poll, LDS
// broadcast) + EXPLICIT AGPR-resident weights. r13-r17 evidence: compiler
// refuses VGPR residency (VGPR_Count 84) and re-streams 256KB/block/step of
// weights from L2 = 144 GB/s/CU = 1.78 us/step — the measured step time
// across four sync structures. AGPR stash removes that stream at the cost of
// 128 v_accvgpr_read/step/thread (~0.2 us/wave-pair).
__global__ __launch_bounds__(512, 1) void rnn_tag(const float* __restrict__ h0,
                                                  const float* __restrict__ Wh,
                                                  float* __restrict__ out,
                                                  uint2* __restrict__ tagbuf){
  float* out_h = out + OUT_SEC;
  const int tid  = threadIdx.x;
  const int lane = tid & 63;
  const int w    = tid >> 6;            // wave 0..7
  const int b    = blockIdx.x >> 4;     // batch
  const int s    = blockIdx.x & 15;     // slice
  const int dbase = s*64 + w*8;

  __shared__ float hbuf[2][DIM];        // 8 KB ping-pong broadcast buffer

  // ---- stash W_h slice (8 rows x 16 cols = 128 floats) into AGPRs ----
  float wa[8][16];                      // each element AGPR-resident (asm-def)
  #pragma unroll
  for (int r = 0; r < 8; ++r)
    #pragma unroll
    for (int j = 0; j < 4; ++j){
      const float4 v = *reinterpret_cast<const float4*>(
          Wh + (size_t)(dbase + r)*DIM + lane*4 + j*256);
      AW(wa[r][4*j+0], v.x);
      AW(wa[r][4*j+1], v.y);
      AW(wa[r][4*j+2], v.z);
      AW(wa[r][4*j+3], v.w);
    }

  // h[0] = h0 in the validated h section (output slot 0)
  if (tid < 16)
    reinterpret_cast<float4*>(out_h + (size_t)b*DIM + s*64)[tid] =
        reinterpret_cast<const float4*>(h0 + (size_t)b*DIM + s*64)[tid];

  const int myrow   = lane >> 3;            // 0..7
  const bool active = ((lane & 7) == 0);    // 8 store lanes per wave

  for (int t = 0; t < T_STEPS; ++t){
    // prefetch pre (h slot t+1) and gate (out slot t) for this lane's row
    float pre_v = 0.f, gate_v = 0.f;
    if (active){
      const size_t d = dbase + myrow;
      pre_v  = out_h[(size_t)(t+1)*BD + (size_t)b*DIM + d];
      gate_v = out  [(size_t)t*BD     + (size_t)b*DIM + d];
    }

    // ---- acquire h[t][b] into LDS (distributed poll, 16B/thread) ----
    if (t == 0){
      const float2 hl = *reinterpret_cast<const float2*>(h0 + (size_t)b*DIM + 2*tid);
      *reinterpret_cast<float2*>(&hbuf[0][2*tid]) = hl;
    } else {
      const uint2* pp = tagbuf + (size_t)(t & 1)*BD + (size_t)b*DIM + 2*tid;
      const unsigned want = (unsigned)t;
      float4 q;
      do {
        asm volatile("global_load_dwordx4 %0, %1, off sc0 sc1\n\t"
                     "s_waitcnt vmcnt(0)"
                     : "=&v"(q) : "v"(pp) : "memory");
      } while (__float_as_uint(q.y) != want || __float_as_uint(q.w) != want);
      *reinterpret_cast<float2*>(&hbuf[t & 1][2*tid]) = make_float2(q.x, q.z);
    }
    __syncthreads();

    const float* src = &hbuf[t & 1][0];
    const float4 hv0 = *reinterpret_cast<const float4*>(src + lane*4);
    const float4 hv1 = *reinterpret_cast<const float4*>(src + 256 + lane*4);
    const float4 hv2 = *reinterpret_cast<const float4*>(src + 512 + lane*4);
    const float4 hv3 = *reinterpret_cast<const float4*>(src + 768 + lane*4);

    // ---- partials: v[r] = dot(W_row, hv); weights read from AGPRs ----
    float v0,v1,v2,v3,v4,v5,v6,v7;
    {
      #define DOTROW(R, OUTV)                                            \
        { float t0,t1,t2,t3,t4,t5,t6,t7,t8,t9,t10,t11,t12,t13,t14,t15;   \
          AR(t0,  wa[R][0]);  AR(t1,  wa[R][1]);                         \
          AR(t2,  wa[R][2]);  AR(t3,  wa[R][3]);                         \
          AR(t4,  wa[R][4]);  AR(t5,  wa[R][5]);                         \
          AR(t6,  wa[R][6]);  AR(t7,  wa[R][7]);                         \
          AR(t8,  wa[R][8]);  AR(t9,  wa[R][9]);                         \
          AR(t10, wa[R][10]); AR(t11, wa[R][11]);                        \
          AR(t12, wa[R][12]); AR(t13, wa[R][13]);                        \
          AR(t14, wa[R][14]); AR(t15, wa[R][15]);                        \
          float a_ = 0.f;                                                \
          a_ = fmaf(t0, hv0.x, fmaf(t1, hv0.y, fmaf(t2, hv0.z, fmaf(t3, hv0.w, a_)))); \
          a_ = fmaf(t4, hv1.x, fmaf(t5, hv1.y, fmaf(t6, hv1.z, fmaf(t7, hv1.w, a_)))); \
          a_ = fmaf(t8, hv2.x, fmaf(t9, hv2.y, fmaf(t10,hv2.z, fmaf(t11,hv2.w, a_)))); \
          a_ = fmaf(t12,hv3.x, fmaf(t13,hv3.y, fmaf(t14,hv3.z, fmaf(t15,hv3.w, a_)))); \
          OUTV = a_; }
      DOTROW(0,v0) DOTROW(1,v1) DOTROW(2,v2) DOTROW(3,v3)
      DOTROW(4,v4) DOTROW(5,v5) DOTROW(6,v6) DOTROW(7,v7)
      #undef DOTROW
    }

    // ---- 10-shuffle folded reduction; lane 8r holds row r ----
    const bool sA = (lane & 32) != 0;
    float a0 = (sA? v4 : v0) + __shfl_xor(sA? v0 : v4, 32, 64);
    float a1 = (sA? v5 : v1) + __shfl_xor(sA? v1 : v5, 32, 64);
    float a2 = (sA? v6 : v2) + __shfl_xor(sA? v2 : v6, 32, 64);
    float a3 = (sA? v7 : v3) + __shfl_xor(sA? v3 : v7, 32, 64);
    const bool sB = (lane & 16) != 0;
    float b0 = (sB? a2 : a0) + __shfl_xor(sB? a0 : a2, 16, 64);
    float b1 = (sB? a3 : a1) + __shfl_xor(sB? a1 : a3, 16, 64);
    const bool sC = (lane & 8) != 0;
    float c0 = (sC? b1 : b0) + __shfl_xor(sC? b0 : b1, 8, 64);
    c0 += __shfl_xor(c0, 4, 64);
    c0 += __shfl_xor(c0, 2, 64);
    c0 += __shfl_xor(c0, 1, 64);

    if (active){
      const float v  = pre_v + c0;
      const float e  = __expf(2.0f * v);
      const float hn = 1.0f - 2.0f / (e + 1.0f);   // tanh(v)
      const size_t d = dbase + myrow;
      if (t != T_STEPS - 1){
        // self-flagging packet (value, t+1) -> ping-pong slot; no drain
        const unsigned long long pkt =
            ((unsigned long long)(unsigned)(t + 1) << 32) |
            (unsigned long long)__float_as_uint(hn);
        __hip_atomic_store(
            reinterpret_cast<unsigned long long*>(
                tagbuf + (size_t)((t + 1) & 1)*BD + (size_t)b*DIM + d),
            pkt, __ATOMIC_RELAXED, __HIP_MEMORY_SCOPE_AGENT);
      }
      // validated h + output (cached; read only after kernel end)
      out_h[(size_t)(t+1)*BD + (size_t)b*DIM + d] = hn;
      out  [(size_t)t*BD     + (size_t)b*DIM + d] = hn * gate_v;
    }
  }
}

// ---------------------------------------------------------------------------
extern "C" void kernel_launch(void* const* d_in, const int* in_sizes, int n_in,
                              void* d_out, int out_size, void* d_ws, size_t ws_size,
                              hipStream_t stream){
  (void)in_sizes; (void)n_in; (void)out_size; (void)ws_size;
  const float* x    = (const float*)d_in[0];
  const float* z    = (const float*)d_in[1];
  const float* h0   = (const float*)d_in[2];
  const float* Wx   = (const float*)d_in[3];
  const float* Wh   = (const float*)d_in[4];
  const float* bias = (const float*)d_in[5];
  float* out   = (float*)d_out;
  float* out_h = out + OUT_SEC;

  hipMemsetAsync(d_ws, 0, TAG_BYTES, stream);
  prep_kernel<<<NB_GEMM + NB_GATE, 256, 0, stream>>>(x, Wx, bias, out_h, z, out);
  rnn_tag    <<<256, 512, 0, stream>>>(h0, Wh, out, (uint2*)d_ws);
}